// Round 15
// baseline (189.611 us; speedup 1.0000x reference)
//
#include <hip/hip_runtime.h>
#include <stdint.h>

#define N_NODES 100000
#define NB 782            // ceil(N_NODES / 128) buckets of 128 nodes
#define NBP 784           // padded
#define BCAP 1536         // max edges per bucket (mean 819, sd 28.6)
#define EPB 3200          // edges per build block (200 blocks x 3200 = 640000)
#define NBLK_CONV 6250    // to_bf16 blocks (1600000 u16x8 / 256)
#define NBLK_W 88         // transpose blocks (22528 / 256)
#define NBLK_HIST 200     // hist blocks

typedef __attribute__((ext_vector_type(8))) short bf16x8;           // 8 bf16 = 4 VGPR
typedef __attribute__((ext_vector_type(4))) float f32x4;
typedef __attribute__((ext_vector_type(8))) unsigned short u16x8;

// ---------------------------------------------------------------- bf16 helpers
__device__ __forceinline__ unsigned short f2bf(float f){
    uint32_t u = __float_as_uint(f);
    uint32_t r = (u + 0x7FFFu + ((u >> 16) & 1u)) >> 16;   // round-nearest-even
    return (unsigned short)r;
}
__device__ __forceinline__ float bf2f(unsigned short h){
    return __uint_as_float(((uint32_t)h) << 16);
}

// ---------------------------------------------------------------- fused preamble
// Independent sections by blockIdx range:
//   [0, NBLK_CONV)                      : x fp32 -> bf16 Xh (8 elems/thread)
//   [NBLK_CONV, NBLK_CONV+NBLK_W)       : W1,W2 -> fragment-order bf16 tables
//   [NBLK_CONV+NBLK_W, +NBLK_HIST)      : per-block LDS histogram of dst>>7
__global__ __launch_bounds__(256) void preamble(const float* __restrict__ x,
        unsigned short* __restrict__ Xh,
        const float* __restrict__ W1, unsigned short* __restrict__ Wtf1,
        const float* __restrict__ W2, unsigned short* __restrict__ Wtf2,
        const int* __restrict__ dst, uint32_t* __restrict__ ghist, int E){
    __shared__ uint32_t h[NBP];
    int bx = blockIdx.x, t = threadIdx.x;
    if (bx < NBLK_CONV){
        int i = bx * 256 + t;
        float4 a = ((const float4*)x)[2 * i];
        float4 b = ((const float4*)x)[2 * i + 1];
        u16x8 o = { f2bf(a.x), f2bf(a.y), f2bf(a.z), f2bf(a.w),
                    f2bf(b.x), f2bf(b.y), f2bf(b.z), f2bf(b.w) };
        ((u16x8*)Xh)[i] = o;
    } else if (bx < NBLK_CONV + NBLK_W){
        const int T1 = 8 * 4 * 64 * 8;   // 16384
        const int T2 = 3 * 4 * 64 * 8;   // 6144
        int i = (bx - NBLK_CONV) * 256 + t;
        if (i < T1){
            int j = i & 7, l = (i >> 3) & 63, st = (i >> 9) & 3, cb = i >> 11;
            int k = st * 32 + (l >> 4) * 8 + j, col = cb * 16 + (l & 15);
            Wtf1[i] = f2bf(W1[(size_t)k * 128 + col]);
        } else if (i < T1 + T2){
            int i2 = i - T1;
            int j = i2 & 7, l = (i2 >> 3) & 63, st = (i2 >> 9) & 3, cb = i2 >> 11;
            int k = st * 32 + (l >> 4) * 8 + j, col = cb * 16 + (l & 15);
            Wtf2[i2] = f2bf((col < 40) ? W2[(size_t)k * 40 + col] : 0.f);
        }
    } else {
        int bl = bx - NBLK_CONV - NBLK_W;
        for (int i = t; i < NBP; i += 256) h[i] = 0u;
        __syncthreads();
        int base = bl * EPB;
        for (int i = t; i < EPB; i += 256){
            int e = base + i;
            if (e < E) atomicAdd(&h[(uint32_t)dst[e] >> 7], 1u);
        }
        __syncthreads();
        for (int i = t; i < NBP; i += 256)
            ghist[bl * NBP + i] = h[i];
    }
}

// P2: one block. Column totals -> hist; exclusive scan -> base; per-(block,bucket)
// start offsets stg[blk][b]. Reads/writes coalesced across threads per iteration.
__global__ __launch_bounds__(1024) void scan_buckets2(const uint32_t* __restrict__ ghist,
        uint32_t* __restrict__ base, uint32_t* __restrict__ hist,
        uint32_t* __restrict__ stg, int nblk){
    __shared__ uint32_t tmp[1024];
    int t = threadIdx.x;
    uint32_t tot = 0u;
    if (t < NB){
        for (int b = 0; b < nblk; b++) tot += ghist[b * NBP + t];
        hist[t] = tot;
    }
    tmp[t] = (t < NB) ? tot : 0u;
    __syncthreads();
    for (int off = 1; off < 1024; off <<= 1){
        uint32_t v = (t >= off) ? tmp[t - off] : 0u;
        __syncthreads();
        tmp[t] += v;
        __syncthreads();
    }
    if (t < NB){
        uint32_t ex = tmp[t] - tot;      // exclusive
        base[t] = ex;
        uint32_t run = ex;
        for (int b = 0; b < nblk; b++){
            stg[b * NBP + t] = run;
            run += ghist[b * NBP + t];
        }
    }
}

// P3: scatter packed edges into bucket-sorted ebuf. No global atomics.
// packed = (dst & 127) << 17 | src   (src < 2^17)
__global__ __launch_bounds__(256) void bucket_scatter2(const int* __restrict__ src,
        const int* __restrict__ dst, const uint32_t* __restrict__ stg,
        uint32_t* __restrict__ ebuf, int E){
    __shared__ uint32_t rank[NBP];
    __shared__ uint32_t stl[NBP];
    int bl = blockIdx.x;
    for (int i = threadIdx.x; i < NBP; i += 256){
        rank[i] = 0u;
        stl[i] = stg[bl * NBP + i];
    }
    __syncthreads();
    int base = bl * EPB;
    for (int i = threadIdx.x; i < EPB; i += 256){
        int e = base + i;
        if (e < E){
            uint32_t d = (uint32_t)dst[e];
            uint32_t b = d >> 7;
            uint32_t r = atomicAdd(&rank[b], 1u);
            ebuf[stl[b] + r] = ((d & 127u) << 17) | (uint32_t)src[e];
        }
    }
}

// P4: per bucket (128 nodes): LDS count -> LDS scan -> offs/cnt/dinv (dense),
// then rank edges per node -> slot within the bucket's contiguous region.
__global__ __launch_bounds__(256) void bucket_csr(const uint32_t* __restrict__ hist,
        const uint32_t* __restrict__ base, const uint32_t* __restrict__ ebuf,
        uint32_t* __restrict__ offs, uint32_t* __restrict__ cnt, float* __restrict__ dinv,
        uint32_t* __restrict__ slot, int N){
    __shared__ uint32_t ebl[BCAP];
    __shared__ uint32_t ncnt[128], loff[128], ncur[128], stmp[128];
    int b = blockIdx.x, t = threadIdx.x;
    uint32_t eb = base[b], ec = hist[b];
    if (ec > BCAP) ec = BCAP;            // unreachable safety
    for (uint32_t i = t; i < ec; i += 256) ebl[i] = ebuf[eb + i];
    if (t < 128){ ncnt[t] = 0u; ncur[t] = 0u; }
    __syncthreads();
    for (uint32_t i = t; i < ec; i += 256) atomicAdd(&ncnt[ebl[i] >> 17], 1u);
    __syncthreads();
    if (t < 128) stmp[t] = ncnt[t];
    __syncthreads();
    for (int off = 1; off < 128; off <<= 1){
        uint32_t v = 0u;
        if (t < 128 && t >= off) v = stmp[t - off];
        __syncthreads();
        if (t < 128) stmp[t] += v;
        __syncthreads();
    }
    if (t < 128) loff[t] = stmp[t] - ncnt[t];    // inclusive -> exclusive
    __syncthreads();
    int g = b * 128 + t;
    if (t < 128 && g < N){
        offs[g] = eb + loff[t];
        cnt[g]  = ncnt[t];
        dinv[g] = rsqrtf((float)(ncnt[t] + 1u));
    }
    for (uint32_t i = t; i < ec; i += 256){
        uint32_t p  = ebl[i];
        uint32_t ld = p >> 17;
        uint32_t r  = atomicAdd(&ncur[ld], 1u);
        slot[eb + loff[ld] + r] = p & 0x1FFFFu;
    }
}

// ---------------------------------------------------------------- aggregation kernel
// OUT[g] = dinv[g] * ( sum dinv[s]*X[s] + dinv[g]*X[g] ), bf16 rows.
// 4 nodes/wave (quarter-lanes), 16 lanes/node, u16x8 = 16B/lane: one row-read
// instruction moves 1KB (4 rows). Index-cache of 16 edges/node; (s,d) via
// __shfl lane (l&48)|(eb+j); volleys of 8 rows/quarter loaded into named
// registers first (32 rows in flight per wave). Padding lanes: idx=0, d=0.
__global__ __launch_bounds__(256) void agg_bf4(const unsigned short* __restrict__ Xh,
        const uint32_t* __restrict__ offs, const uint32_t* __restrict__ cnt,
        const uint32_t* __restrict__ slot, const float* __restrict__ dinv,
        unsigned short* __restrict__ OUT){
    int wgid = blockIdx.x * 4 + (threadIdx.x >> 6);
    int l = threadIdx.x & 63;
    int ql = l & 15;
    int g = wgid * 4 + (l >> 4);                     // node id (grid exact)
    const u16x8* X8 = (const u16x8*)Xh;              // 16 u16x8 per 128-feat row
    uint32_t o = offs[g], c = cnt[g];
    float acc[8] = {};
    #pragma unroll 1
    for (uint32_t base = 0; base < c; base += 16){
        int rem = (int)(c - base); if (rem > 16) rem = 16;
        uint32_t idx = 0u; float ds = 0.f;
        if (ql < rem){
            idx = slot[o + base + (uint32_t)ql];
            ds = dinv[idx];
        }
        int groups = (rem + 7) >> 3;
        #pragma unroll 1
        for (int gq = 0; gq < groups; gq++){
            int eb = gq * 8;
            u16x8 v[8]; float d[8];
            #pragma unroll
            for (int j = 0; j < 8; j++){
                int srcl = (l & 48) | (eb + j);
                uint32_t s = (uint32_t)__shfl((int)idx, srcl, 64);
                d[j] = __shfl(ds, srcl, 64);
                v[j] = X8[(size_t)s * 16 + ql];
            }
            #pragma unroll
            for (int j = 0; j < 8; j++){
                #pragma unroll
                for (int f = 0; f < 8; f++)
                    acc[f] += d[j] * bf2f(v[j][f]);
            }
        }
    }
    float dd = dinv[g];
    u16x8 sv = X8[(size_t)g * 16 + ql];
    u16x8 r;
    #pragma unroll
    for (int f = 0; f < 8; f++)
        r[f] = f2bf(dd * (acc[f] + dd * bf2f(sv[f])));
    ((u16x8*)OUT)[(size_t)g * 16 + ql] = r;
}

// ---------------------------------------------------------------- MFMA GEMM layer 1
// OUT = bf16( relu( Xagg @ W1 + b1 ) ). 4 waves/block, wave = 16 rows x 128 cols.
// Software pipeline with named register banks; B frags are single coalesced 1KB
// loads from fragment-order Wtf (L1/L2 resident).
__global__ __launch_bounds__(256) void gemm_mfma_l1(const unsigned short* __restrict__ Xagg,
        const unsigned short* __restrict__ Wtf, const float* __restrict__ bias,
        unsigned short* __restrict__ OUT){
    int tid = threadIdx.x;
    int wid = tid >> 6, l = tid & 63;
    int lm = l & 15, lk = l >> 4;
    int rw = blockIdx.x * 64 + wid * 16;
    int ra = rw + lm; ra = ra < N_NODES ? ra : N_NODES - 1;
    const bf16x8* Wv = (const bf16x8*)Wtf;

    f32x4 acc[8] = {};
    bf16x8 aA, aB, bA[8], bB[8];

    aA = *(const bf16x8*)(Xagg + (size_t)ra * 128 + lk * 8);
    #pragma unroll
    for (int cb = 0; cb < 8; cb++) bA[cb] = Wv[(size_t)(cb * 4 + 0) * 64 + l];

    aB = *(const bf16x8*)(Xagg + (size_t)ra * 128 + 32 + lk * 8);
    #pragma unroll
    for (int cb = 0; cb < 8; cb++) bB[cb] = Wv[(size_t)(cb * 4 + 1) * 64 + l];
    #pragma unroll
    for (int cb = 0; cb < 8; cb++)
        acc[cb] = __builtin_amdgcn_mfma_f32_16x16x32_bf16(aA, bA[cb], acc[cb], 0, 0, 0);

    aA = *(const bf16x8*)(Xagg + (size_t)ra * 128 + 64 + lk * 8);
    #pragma unroll
    for (int cb = 0; cb < 8; cb++) bA[cb] = Wv[(size_t)(cb * 4 + 2) * 64 + l];
    #pragma unroll
    for (int cb = 0; cb < 8; cb++)
        acc[cb] = __builtin_amdgcn_mfma_f32_16x16x32_bf16(aB, bB[cb], acc[cb], 0, 0, 0);

    aB = *(const bf16x8*)(Xagg + (size_t)ra * 128 + 96 + lk * 8);
    #pragma unroll
    for (int cb = 0; cb < 8; cb++) bB[cb] = Wv[(size_t)(cb * 4 + 3) * 64 + l];
    #pragma unroll
    for (int cb = 0; cb < 8; cb++)
        acc[cb] = __builtin_amdgcn_mfma_f32_16x16x32_bf16(aA, bA[cb], acc[cb], 0, 0, 0);

    #pragma unroll
    for (int cb = 0; cb < 8; cb++)
        acc[cb] = __builtin_amdgcn_mfma_f32_16x16x32_bf16(aB, bB[cb], acc[cb], 0, 0, 0);

    #pragma unroll
    for (int cb = 0; cb < 8; cb++){
        int col = cb * 16 + lm;
        float bs = bias[col];
        #pragma unroll
        for (int i = 0; i < 4; i++){
            int row = rw + lk * 4 + i;
            if (row < N_NODES)
                OUT[(size_t)row * 128 + col] = f2bf(fmaxf(acc[cb][i] + bs, 0.f));
        }
    }
}

// ---------------------------------------------------------------- MFMA GEMM layer 2
// OUT = Aagg @ W2 + b2 (fp32, 40 cols; Wtf2 padded to 48 cols with zeros).
__global__ __launch_bounds__(256) void gemm_mfma_l2(const unsigned short* __restrict__ Aagg,
        const unsigned short* __restrict__ Wtf, const float* __restrict__ bias,
        float* __restrict__ OUT){
    int tid = threadIdx.x;
    int wid = tid >> 6, l = tid & 63;
    int lm = l & 15, lk = l >> 4;
    int rw = blockIdx.x * 64 + wid * 16;
    int ra = rw + lm; ra = ra < N_NODES ? ra : N_NODES - 1;
    const bf16x8* Wv = (const bf16x8*)Wtf;

    f32x4 acc[3] = {};
    bf16x8 aA, aB, bA[3], bB[3];

    aA = *(const bf16x8*)(Aagg + (size_t)ra * 128 + lk * 8);
    #pragma unroll
    for (int cb = 0; cb < 3; cb++) bA[cb] = Wv[(size_t)(cb * 4 + 0) * 64 + l];

    aB = *(const bf16x8*)(Aagg + (size_t)ra * 128 + 32 + lk * 8);
    #pragma unroll
    for (int cb = 0; cb < 3; cb++) bB[cb] = Wv[(size_t)(cb * 4 + 1) * 64 + l];
    #pragma unroll
    for (int cb = 0; cb < 3; cb++)
        acc[cb] = __builtin_amdgcn_mfma_f32_16x16x32_bf16(aA, bA[cb], acc[cb], 0, 0, 0);

    aA = *(const bf16x8*)(Aagg + (size_t)ra * 128 + 64 + lk * 8);
    #pragma unroll
    for (int cb = 0; cb < 3; cb++) bA[cb] = Wv[(size_t)(cb * 4 + 2) * 64 + l];
    #pragma unroll
    for (int cb = 0; cb < 3; cb++)
        acc[cb] = __builtin_amdgcn_mfma_f32_16x16x32_bf16(aB, bB[cb], acc[cb], 0, 0, 0);

    aB = *(const bf16x8*)(Aagg + (size_t)ra * 128 + 96 + lk * 8);
    #pragma unroll
    for (int cb = 0; cb < 3; cb++) bB[cb] = Wv[(size_t)(cb * 4 + 3) * 64 + l];
    #pragma unroll
    for (int cb = 0; cb < 3; cb++)
        acc[cb] = __builtin_amdgcn_mfma_f32_16x16x32_bf16(aA, bA[cb], acc[cb], 0, 0, 0);

    #pragma unroll
    for (int cb = 0; cb < 3; cb++)
        acc[cb] = __builtin_amdgcn_mfma_f32_16x16x32_bf16(aB, bB[cb], acc[cb], 0, 0, 0);

    #pragma unroll
    for (int cb = 0; cb < 3; cb++){
        int col = cb * 16 + lm;
        if (col < 40){
            float bs = bias[col];
            #pragma unroll
            for (int i = 0; i < 4; i++){
                int row = rw + lk * 4 + i;
                if (row < N_NODES) OUT[(size_t)row * 40 + col] = acc[cb][i] + bs;
            }
        }
    }
}

// ---------------------------------------------------------------- launch
extern "C" void kernel_launch(void* const* d_in, const int* in_sizes, int n_in,
                              void* d_out, int out_size, void* d_ws, size_t ws_size,
                              hipStream_t stream) {
    const float* x   = (const float*)d_in[0];
    const int*   ei  = (const int*)d_in[1];      // int32 (harness converts integer inputs)
    const float* W1  = (const float*)d_in[2];
    const float* b1  = (const float*)d_in[3];
    const float* W2  = (const float*)d_in[4];
    const float* b2  = (const float*)d_in[5];
    float*       out = (float*)d_out;

    const int N = N_NODES;
    const int E = in_sizes[1] / 2;
    const int* src = ei;
    const int* dst = ei + E;

    // workspace carve-up (512B-aligned). ~83 MiB total (Xh aliased as Aagg2).
    char* ws = (char*)d_ws;
    size_t o = 0;
    auto alloc = [&](size_t bytes) -> char* {
        char* p = ws + o;
        o += (bytes + 511) & ~(size_t)511;
        return p;
    };
    const int nblk_edge = (E + EPB - 1) / EPB;    // 200
    uint32_t*       ghist = (uint32_t*)alloc((size_t)nblk_edge * NBP * 4);
    uint32_t*       stg   = (uint32_t*)alloc((size_t)nblk_edge * NBP * 4);
    uint32_t*       hist  = (uint32_t*)alloc((size_t)NBP * 4);
    uint32_t*       bbase = (uint32_t*)alloc((size_t)NBP * 4);
    uint32_t*       ebuf  = (uint32_t*)alloc((size_t)E * 4);
    uint32_t*       offs  = (uint32_t*)alloc((size_t)N * 4);
    uint32_t*       cnt   = (uint32_t*)alloc((size_t)N * 4);
    uint32_t*       slot  = (uint32_t*)alloc((size_t)E * 4);
    float*          dinv  = (float*)alloc((size_t)N * 4);
    unsigned short* Wtf1  = (unsigned short*)alloc((size_t)8 * 4 * 64 * 8 * 2);  // 32 KB
    unsigned short* Wtf2  = (unsigned short*)alloc((size_t)3 * 4 * 64 * 8 * 2);  // 12 KB
    unsigned short* Xh    = (unsigned short*)alloc((size_t)N * 128 * 2);  // bf16 x; later Aagg2
    unsigned short* Xagg  = (unsigned short*)alloc((size_t)N * 128 * 2);  // aggregated x (bf16)
    unsigned short* Ah    = (unsigned short*)alloc((size_t)N * 128 * 2);  // layer-1 act (bf16)
    unsigned short* Aagg2 = Xh;   // Xh dead after agg1; reuse

    const int nblk_agg = N / 16;                  // 6250: 4 waves x 4 nodes/wave
    const int nblk_gemm = (N + 63) / 64;          // 1563

    // --- fused preamble (convert + W transpose + histogram) ---
    preamble<<<NBLK_CONV + NBLK_W + NBLK_HIST, 256, 0, stream>>>(
        x, Xh, W1, Wtf1, W2, Wtf2, dst, ghist, E);
    scan_buckets2<<<1, 1024, 0, stream>>>(ghist, bbase, hist, stg, nblk_edge);
    bucket_scatter2<<<nblk_edge, 256, 0, stream>>>(src, dst, stg, ebuf, E);
    bucket_csr<<<NB, 256, 0, stream>>>(hist, bbase, ebuf, offs, cnt, dinv, slot, N);

    // --- layer 1 ---
    agg_bf4<<<nblk_agg, 256, 0, stream>>>(Xh, offs, cnt, slot, dinv, Xagg);
    gemm_mfma_l1<<<nblk_gemm, 256, 0, stream>>>(Xagg, Wtf1, b1, Ah);

    // --- layer 2 ---
    agg_bf4<<<nblk_agg, 256, 0, stream>>>(Ah, offs, cnt, slot, dinv, Aagg2);
    gemm_mfma_l2<<<nblk_gemm, 256, 0, stream>>>(Aagg2, Wtf2, b2, out);
}

// Round 16
// 140.961 us; speedup vs baseline: 1.3451x; 1.3451x over previous
//
#include <hip/hip_runtime.h>
#include <stdint.h>

#define N_NODES 100000
#define NB 782            // ceil(N_NODES / 128) buckets of 128 nodes
#define NBP 784           // padded
#define BCAP 1536         // max edges per bucket (mean 819, sd 28.6)
#define EPB 3200          // edges per build block (200 blocks x 3200 = 640000)
#define NBLK_CONV 6250    // to_bf16 blocks (1600000 u16x8 / 256)
#define NBLK_W 88         // transpose blocks (22528 / 256)
#define NBLK_HIST 200     // hist blocks

typedef __attribute__((ext_vector_type(8))) short bf16x8;           // 8 bf16 = 4 VGPR
typedef __attribute__((ext_vector_type(4))) float f32x4;
typedef __attribute__((ext_vector_type(8))) unsigned short u16x8;

// ---------------------------------------------------------------- bf16 helpers
__device__ __forceinline__ unsigned short f2bf(float f){
    uint32_t u = __float_as_uint(f);
    uint32_t r = (u + 0x7FFFu + ((u >> 16) & 1u)) >> 16;   // round-nearest-even
    return (unsigned short)r;
}
__device__ __forceinline__ float bf2f(unsigned short h){
    return __uint_as_float(((uint32_t)h) << 16);
}

// ---------------------------------------------------------------- fused preamble
// Independent sections by blockIdx range:
//   [0, NBLK_CONV)                      : x fp32 -> bf16 Xh (8 elems/thread)
//   [NBLK_CONV, NBLK_CONV+NBLK_W)       : W1,W2 -> fragment-order bf16 tables
//   [NBLK_CONV+NBLK_W, +NBLK_HIST)      : per-block LDS histogram of dst>>7
__global__ __launch_bounds__(256) void preamble(const float* __restrict__ x,
        unsigned short* __restrict__ Xh,
        const float* __restrict__ W1, unsigned short* __restrict__ Wtf1,
        const float* __restrict__ W2, unsigned short* __restrict__ Wtf2,
        const int* __restrict__ dst, uint32_t* __restrict__ ghist, int E){
    __shared__ uint32_t h[NBP];
    int bx = blockIdx.x, t = threadIdx.x;
    if (bx < NBLK_CONV){
        int i = bx * 256 + t;
        float4 a = ((const float4*)x)[2 * i];
        float4 b = ((const float4*)x)[2 * i + 1];
        u16x8 o = { f2bf(a.x), f2bf(a.y), f2bf(a.z), f2bf(a.w),
                    f2bf(b.x), f2bf(b.y), f2bf(b.z), f2bf(b.w) };
        ((u16x8*)Xh)[i] = o;
    } else if (bx < NBLK_CONV + NBLK_W){
        const int T1 = 8 * 4 * 64 * 8;   // 16384
        const int T2 = 3 * 4 * 64 * 8;   // 6144
        int i = (bx - NBLK_CONV) * 256 + t;
        if (i < T1){
            int j = i & 7, l = (i >> 3) & 63, st = (i >> 9) & 3, cb = i >> 11;
            int k = st * 32 + (l >> 4) * 8 + j, col = cb * 16 + (l & 15);
            Wtf1[i] = f2bf(W1[(size_t)k * 128 + col]);
        } else if (i < T1 + T2){
            int i2 = i - T1;
            int j = i2 & 7, l = (i2 >> 3) & 63, st = (i2 >> 9) & 3, cb = i2 >> 11;
            int k = st * 32 + (l >> 4) * 8 + j, col = cb * 16 + (l & 15);
            Wtf2[i2] = f2bf((col < 40) ? W2[(size_t)k * 40 + col] : 0.f);
        }
    } else {
        int bl = bx - NBLK_CONV - NBLK_W;
        for (int i = t; i < NBP; i += 256) h[i] = 0u;
        __syncthreads();
        int base = bl * EPB;
        for (int i = t; i < EPB; i += 256){
            int e = base + i;
            if (e < E) atomicAdd(&h[(uint32_t)dst[e] >> 7], 1u);
        }
        __syncthreads();
        for (int i = t; i < NBP; i += 256)
            ghist[bl * NBP + i] = h[i];
    }
}

// P2a: one block PER BUCKET: exclusive scan over the nblk per-block counts of
// this bucket (parallel across 782 CU-blocks; fixes round-15's 57us serial scan).
// part[blk][b] = prefix of blocks < blk for bucket b; hist[b] = total.
__global__ __launch_bounds__(256) void scan_blkcol(const uint32_t* __restrict__ ghist,
        uint32_t* __restrict__ part, uint32_t* __restrict__ hist, int nblk){
    __shared__ uint32_t tmp[256];
    int b = blockIdx.x, t = threadIdx.x;
    uint32_t v = (t < nblk) ? ghist[(size_t)t * NBP + b] : 0u;   // nblk = 200 <= 256
    tmp[t] = v;
    __syncthreads();
    for (int off = 1; off < 256; off <<= 1){
        uint32_t u = (t >= off) ? tmp[t - off] : 0u;
        __syncthreads();
        tmp[t] += u;
        __syncthreads();
    }
    if (t < nblk) part[(size_t)t * NBP + b] = tmp[t] - v;   // exclusive within column
    if (t == 0) hist[b] = tmp[255];                          // column total
}

// P2b: one block: exclusive scan of the NB bucket totals -> base.
__global__ __launch_bounds__(1024) void scan_base(const uint32_t* __restrict__ hist,
        uint32_t* __restrict__ base){
    __shared__ uint32_t tmp[1024];
    int t = threadIdx.x;
    uint32_t v = (t < NB) ? hist[t] : 0u;
    tmp[t] = v;
    __syncthreads();
    for (int off = 1; off < 1024; off <<= 1){
        uint32_t u = (t >= off) ? tmp[t - off] : 0u;
        __syncthreads();
        tmp[t] += u;
        __syncthreads();
    }
    if (t < NB) base[t] = tmp[t] - v;
}

// P3: scatter packed edges into bucket-sorted ebuf. No global atomics: block's
// start per bucket = base[b] + part[bl][b]; LDS atomics rank within block.
// packed = (dst & 127) << 17 | src   (src < 2^17)
__global__ __launch_bounds__(256) void bucket_scatter2(const int* __restrict__ src,
        const int* __restrict__ dst, const uint32_t* __restrict__ base,
        const uint32_t* __restrict__ part, uint32_t* __restrict__ ebuf, int E){
    __shared__ uint32_t rank[NBP];
    __shared__ uint32_t stl[NBP];
    int bl = blockIdx.x;
    for (int i = threadIdx.x; i < NBP; i += 256){
        rank[i] = 0u;
        stl[i] = base[i] + part[(size_t)bl * NBP + i];
    }
    __syncthreads();
    int eb0 = bl * EPB;
    for (int i = threadIdx.x; i < EPB; i += 256){
        int e = eb0 + i;
        if (e < E){
            uint32_t d = (uint32_t)dst[e];
            uint32_t b = d >> 7;
            uint32_t r = atomicAdd(&rank[b], 1u);
            ebuf[stl[b] + r] = ((d & 127u) << 17) | (uint32_t)src[e];
        }
    }
}

// P4: per bucket (128 nodes): LDS count -> LDS scan -> offs/cnt/dinv (dense),
// then rank edges per node -> slot within the bucket's contiguous region.
__global__ __launch_bounds__(256) void bucket_csr(const uint32_t* __restrict__ hist,
        const uint32_t* __restrict__ base, const uint32_t* __restrict__ ebuf,
        uint32_t* __restrict__ offs, uint32_t* __restrict__ cnt, float* __restrict__ dinv,
        uint32_t* __restrict__ slot, int N){
    __shared__ uint32_t ebl[BCAP];
    __shared__ uint32_t ncnt[128], loff[128], ncur[128], stmp[128];
    int b = blockIdx.x, t = threadIdx.x;
    uint32_t eb = base[b], ec = hist[b];
    if (ec > BCAP) ec = BCAP;            // unreachable safety
    for (uint32_t i = t; i < ec; i += 256) ebl[i] = ebuf[eb + i];
    if (t < 128){ ncnt[t] = 0u; ncur[t] = 0u; }
    __syncthreads();
    for (uint32_t i = t; i < ec; i += 256) atomicAdd(&ncnt[ebl[i] >> 17], 1u);
    __syncthreads();
    if (t < 128) stmp[t] = ncnt[t];
    __syncthreads();
    for (int off = 1; off < 128; off <<= 1){
        uint32_t v = 0u;
        if (t < 128 && t >= off) v = stmp[t - off];
        __syncthreads();
        if (t < 128) stmp[t] += v;
        __syncthreads();
    }
    if (t < 128) loff[t] = stmp[t] - ncnt[t];    // inclusive -> exclusive
    __syncthreads();
    int g = b * 128 + t;
    if (t < 128 && g < N){
        offs[g] = eb + loff[t];
        cnt[g]  = ncnt[t];
        dinv[g] = rsqrtf((float)(ncnt[t] + 1u));
    }
    for (uint32_t i = t; i < ec; i += 256){
        uint32_t p  = ebl[i];
        uint32_t ld = p >> 17;
        uint32_t r  = atomicAdd(&ncur[ld], 1u);
        slot[eb + loff[ld] + r] = p & 0x1FFFFu;
    }
}

// ---------------------------------------------------------------- aggregation kernel
// OUT[g] = dinv[g] * ( sum dinv[s]*X[s] + dinv[g]*X[g] ), bf16 rows.
// 4 nodes/wave (quarter-lanes), 16 lanes/node, u16x8 = 16B/lane: one row-read
// instruction moves 1KB (4 rows). Index-cache of 16 edges/node; (s,d) via
// __shfl lane (l&48)|(eb+j); volleys of 8 rows/quarter loaded into named
// registers first. Padding lanes: idx=0, d=0.
__global__ __launch_bounds__(256) void agg_bf4(const unsigned short* __restrict__ Xh,
        const uint32_t* __restrict__ offs, const uint32_t* __restrict__ cnt,
        const uint32_t* __restrict__ slot, const float* __restrict__ dinv,
        unsigned short* __restrict__ OUT){
    int wgid = blockIdx.x * 4 + (threadIdx.x >> 6);
    int l = threadIdx.x & 63;
    int ql = l & 15;
    int g = wgid * 4 + (l >> 4);                     // node id (grid exact)
    const u16x8* X8 = (const u16x8*)Xh;              // 16 u16x8 per 128-feat row
    uint32_t o = offs[g], c = cnt[g];
    float acc[8] = {};
    #pragma unroll 1
    for (uint32_t base = 0; base < c; base += 16){
        int rem = (int)(c - base); if (rem > 16) rem = 16;
        uint32_t idx = 0u; float ds = 0.f;
        if (ql < rem){
            idx = slot[o + base + (uint32_t)ql];
            ds = dinv[idx];
        }
        int groups = (rem + 7) >> 3;
        #pragma unroll 1
        for (int gq = 0; gq < groups; gq++){
            int eb = gq * 8;
            u16x8 v[8]; float d[8];
            #pragma unroll
            for (int j = 0; j < 8; j++){
                int srcl = (l & 48) | (eb + j);
                uint32_t s = (uint32_t)__shfl((int)idx, srcl, 64);
                d[j] = __shfl(ds, srcl, 64);
                v[j] = X8[(size_t)s * 16 + ql];
            }
            #pragma unroll
            for (int j = 0; j < 8; j++){
                #pragma unroll
                for (int f = 0; f < 8; f++)
                    acc[f] += d[j] * bf2f(v[j][f]);
            }
        }
    }
    float dd = dinv[g];
    u16x8 sv = X8[(size_t)g * 16 + ql];
    u16x8 r;
    #pragma unroll
    for (int f = 0; f < 8; f++)
        r[f] = f2bf(dd * (acc[f] + dd * bf2f(sv[f])));
    ((u16x8*)OUT)[(size_t)g * 16 + ql] = r;
}

// ---------------------------------------------------------------- MFMA GEMM layer 1
// OUT = bf16( relu( Xagg @ W1 + b1 ) ). 4 waves/block, wave = 16 rows x 128 cols.
// Software pipeline with named register banks; B frags are single coalesced 1KB
// loads from fragment-order Wtf (L1/L2 resident).
__global__ __launch_bounds__(256) void gemm_mfma_l1(const unsigned short* __restrict__ Xagg,
        const unsigned short* __restrict__ Wtf, const float* __restrict__ bias,
        unsigned short* __restrict__ OUT){
    int tid = threadIdx.x;
    int wid = tid >> 6, l = tid & 63;
    int lm = l & 15, lk = l >> 4;
    int rw = blockIdx.x * 64 + wid * 16;
    int ra = rw + lm; ra = ra < N_NODES ? ra : N_NODES - 1;
    const bf16x8* Wv = (const bf16x8*)Wtf;

    f32x4 acc[8] = {};
    bf16x8 aA, aB, bA[8], bB[8];

    aA = *(const bf16x8*)(Xagg + (size_t)ra * 128 + lk * 8);
    #pragma unroll
    for (int cb = 0; cb < 8; cb++) bA[cb] = Wv[(size_t)(cb * 4 + 0) * 64 + l];

    aB = *(const bf16x8*)(Xagg + (size_t)ra * 128 + 32 + lk * 8);
    #pragma unroll
    for (int cb = 0; cb < 8; cb++) bB[cb] = Wv[(size_t)(cb * 4 + 1) * 64 + l];
    #pragma unroll
    for (int cb = 0; cb < 8; cb++)
        acc[cb] = __builtin_amdgcn_mfma_f32_16x16x32_bf16(aA, bA[cb], acc[cb], 0, 0, 0);

    aA = *(const bf16x8*)(Xagg + (size_t)ra * 128 + 64 + lk * 8);
    #pragma unroll
    for (int cb = 0; cb < 8; cb++) bA[cb] = Wv[(size_t)(cb * 4 + 2) * 64 + l];
    #pragma unroll
    for (int cb = 0; cb < 8; cb++)
        acc[cb] = __builtin_amdgcn_mfma_f32_16x16x32_bf16(aB, bB[cb], acc[cb], 0, 0, 0);

    aB = *(const bf16x8*)(Xagg + (size_t)ra * 128 + 96 + lk * 8);
    #pragma unroll
    for (int cb = 0; cb < 8; cb++) bB[cb] = Wv[(size_t)(cb * 4 + 3) * 64 + l];
    #pragma unroll
    for (int cb = 0; cb < 8; cb++)
        acc[cb] = __builtin_amdgcn_mfma_f32_16x16x32_bf16(aA, bA[cb], acc[cb], 0, 0, 0);

    #pragma unroll
    for (int cb = 0; cb < 8; cb++)
        acc[cb] = __builtin_amdgcn_mfma_f32_16x16x32_bf16(aB, bB[cb], acc[cb], 0, 0, 0);

    #pragma unroll
    for (int cb = 0; cb < 8; cb++){
        int col = cb * 16 + lm;
        float bs = bias[col];
        #pragma unroll
        for (int i = 0; i < 4; i++){
            int row = rw + lk * 4 + i;
            if (row < N_NODES)
                OUT[(size_t)row * 128 + col] = f2bf(fmaxf(acc[cb][i] + bs, 0.f));
        }
    }
}

// ---------------------------------------------------------------- MFMA GEMM layer 2
// OUT = Aagg @ W2 + b2 (fp32, 40 cols; Wtf2 padded to 48 cols with zeros).
__global__ __launch_bounds__(256) void gemm_mfma_l2(const unsigned short* __restrict__ Aagg,
        const unsigned short* __restrict__ Wtf, const float* __restrict__ bias,
        float* __restrict__ OUT){
    int tid = threadIdx.x;
    int wid = tid >> 6, l = tid & 63;
    int lm = l & 15, lk = l >> 4;
    int rw = blockIdx.x * 64 + wid * 16;
    int ra = rw + lm; ra = ra < N_NODES ? ra : N_NODES - 1;
    const bf16x8* Wv = (const bf16x8*)Wtf;

    f32x4 acc[3] = {};
    bf16x8 aA, aB, bA[3], bB[3];

    aA = *(const bf16x8*)(Aagg + (size_t)ra * 128 + lk * 8);
    #pragma unroll
    for (int cb = 0; cb < 3; cb++) bA[cb] = Wv[(size_t)(cb * 4 + 0) * 64 + l];

    aB = *(const bf16x8*)(Aagg + (size_t)ra * 128 + 32 + lk * 8);
    #pragma unroll
    for (int cb = 0; cb < 3; cb++) bB[cb] = Wv[(size_t)(cb * 4 + 1) * 64 + l];
    #pragma unroll
    for (int cb = 0; cb < 3; cb++)
        acc[cb] = __builtin_amdgcn_mfma_f32_16x16x32_bf16(aA, bA[cb], acc[cb], 0, 0, 0);

    aA = *(const bf16x8*)(Aagg + (size_t)ra * 128 + 64 + lk * 8);
    #pragma unroll
    for (int cb = 0; cb < 3; cb++) bA[cb] = Wv[(size_t)(cb * 4 + 2) * 64 + l];
    #pragma unroll
    for (int cb = 0; cb < 3; cb++)
        acc[cb] = __builtin_amdgcn_mfma_f32_16x16x32_bf16(aB, bB[cb], acc[cb], 0, 0, 0);

    aB = *(const bf16x8*)(Aagg + (size_t)ra * 128 + 96 + lk * 8);
    #pragma unroll
    for (int cb = 0; cb < 3; cb++) bB[cb] = Wv[(size_t)(cb * 4 + 3) * 64 + l];
    #pragma unroll
    for (int cb = 0; cb < 3; cb++)
        acc[cb] = __builtin_amdgcn_mfma_f32_16x16x32_bf16(aA, bA[cb], acc[cb], 0, 0, 0);

    #pragma unroll
    for (int cb = 0; cb < 3; cb++)
        acc[cb] = __builtin_amdgcn_mfma_f32_16x16x32_bf16(aB, bB[cb], acc[cb], 0, 0, 0);

    #pragma unroll
    for (int cb = 0; cb < 3; cb++){
        int col = cb * 16 + lm;
        if (col < 40){
            float bs = bias[col];
            #pragma unroll
            for (int i = 0; i < 4; i++){
                int row = rw + lk * 4 + i;
                if (row < N_NODES) OUT[(size_t)row * 40 + col] = acc[cb][i] + bs;
            }
        }
    }
}

// ---------------------------------------------------------------- launch
extern "C" void kernel_launch(void* const* d_in, const int* in_sizes, int n_in,
                              void* d_out, int out_size, void* d_ws, size_t ws_size,
                              hipStream_t stream) {
    const float* x   = (const float*)d_in[0];
    const int*   ei  = (const int*)d_in[1];      // int32 (harness converts integer inputs)
    const float* W1  = (const float*)d_in[2];
    const float* b1  = (const float*)d_in[3];
    const float* W2  = (const float*)d_in[4];
    const float* b2  = (const float*)d_in[5];
    float*       out = (float*)d_out;

    const int N = N_NODES;
    const int E = in_sizes[1] / 2;
    const int* src = ei;
    const int* dst = ei + E;

    // workspace carve-up (512B-aligned). ~83 MiB total (Xh aliased as Aagg2).
    char* ws = (char*)d_ws;
    size_t o = 0;
    auto alloc = [&](size_t bytes) -> char* {
        char* p = ws + o;
        o += (bytes + 511) & ~(size_t)511;
        return p;
    };
    const int nblk_edge = (E + EPB - 1) / EPB;    // 200
    uint32_t*       ghist = (uint32_t*)alloc((size_t)nblk_edge * NBP * 4);
    uint32_t*       part  = (uint32_t*)alloc((size_t)nblk_edge * NBP * 4);
    uint32_t*       hist  = (uint32_t*)alloc((size_t)NBP * 4);
    uint32_t*       bbase = (uint32_t*)alloc((size_t)NBP * 4);
    uint32_t*       ebuf  = (uint32_t*)alloc((size_t)E * 4);
    uint32_t*       offs  = (uint32_t*)alloc((size_t)N * 4);
    uint32_t*       cnt   = (uint32_t*)alloc((size_t)N * 4);
    uint32_t*       slot  = (uint32_t*)alloc((size_t)E * 4);
    float*          dinv  = (float*)alloc((size_t)N * 4);
    unsigned short* Wtf1  = (unsigned short*)alloc((size_t)8 * 4 * 64 * 8 * 2);  // 32 KB
    unsigned short* Wtf2  = (unsigned short*)alloc((size_t)3 * 4 * 64 * 8 * 2);  // 12 KB
    unsigned short* Xh    = (unsigned short*)alloc((size_t)N * 128 * 2);  // bf16 x; later Aagg2
    unsigned short* Xagg  = (unsigned short*)alloc((size_t)N * 128 * 2);  // aggregated x (bf16)
    unsigned short* Ah    = (unsigned short*)alloc((size_t)N * 128 * 2);  // layer-1 act (bf16)
    unsigned short* Aagg2 = Xh;   // Xh dead after agg1; reuse

    const int nblk_agg = N / 16;                  // 6250: 4 waves x 4 nodes/wave
    const int nblk_gemm = (N + 63) / 64;          // 1563

    // --- fused preamble (convert + W transpose + histogram) ---
    preamble<<<NBLK_CONV + NBLK_W + NBLK_HIST, 256, 0, stream>>>(
        x, Xh, W1, Wtf1, W2, Wtf2, dst, ghist, E);
    scan_blkcol<<<NB, 256, 0, stream>>>(ghist, part, hist, nblk_edge);
    scan_base<<<1, 1024, 0, stream>>>(hist, bbase);
    bucket_scatter2<<<nblk_edge, 256, 0, stream>>>(src, dst, bbase, part, ebuf, E);
    bucket_csr<<<NB, 256, 0, stream>>>(hist, bbase, ebuf, offs, cnt, dinv, slot, N);

    // --- layer 1 ---
    agg_bf4<<<nblk_agg, 256, 0, stream>>>(Xh, offs, cnt, slot, dinv, Xagg);
    gemm_mfma_l1<<<nblk_gemm, 256, 0, stream>>>(Xagg, Wtf1, b1, Ah);

    // --- layer 2 ---
    agg_bf4<<<nblk_agg, 256, 0, stream>>>(Ah, offs, cnt, slot, dinv, Aagg2);
    gemm_mfma_l2<<<nblk_gemm, 256, 0, stream>>>(Aagg2, Wtf2, b2, out);
}

// Round 17
// 140.245 us; speedup vs baseline: 1.3520x; 1.0051x over previous
//
#include <hip/hip_runtime.h>
#include <stdint.h>

#define N_NODES 100000
#define NB 782            // ceil(N_NODES / 128) buckets of 128 nodes
#define NBP 784           // padded
#define BCAP 1536         // max edges per bucket (mean 819, sd 28.6)
#define EPB 3200          // edges per build block (200 blocks x 3200 = 640000)
#define NBLK_CONV 6250    // to_bf16 blocks (1600000 u16x8 / 256)
#define NBLK_W 88         // transpose blocks (22528 / 256)
#define NBLK_HIST 200     // hist blocks

typedef __attribute__((ext_vector_type(8))) short bf16x8;           // 8 bf16 = 4 VGPR
typedef __attribute__((ext_vector_type(4))) float f32x4;
typedef __attribute__((ext_vector_type(8))) unsigned short u16x8;

// ---------------------------------------------------------------- bf16 helpers
__device__ __forceinline__ unsigned short f2bf(float f){
    uint32_t u = __float_as_uint(f);
    uint32_t r = (u + 0x7FFFu + ((u >> 16) & 1u)) >> 16;   // round-nearest-even
    return (unsigned short)r;
}
__device__ __forceinline__ float bf2f(unsigned short h){
    return __uint_as_float(((uint32_t)h) << 16);
}

// ---------------------------------------------------------------- fused preamble
// Independent sections by blockIdx range:
//   [0, NBLK_CONV)                      : x fp32 -> bf16 Xh (8 elems/thread)
//   [NBLK_CONV, NBLK_CONV+NBLK_W)       : W1,W2 -> fragment-order bf16 tables
//   [NBLK_CONV+NBLK_W, +NBLK_HIST)      : per-block LDS histogram of dst>>7
__global__ __launch_bounds__(256) void preamble(const float* __restrict__ x,
        unsigned short* __restrict__ Xh,
        const float* __restrict__ W1, unsigned short* __restrict__ Wtf1,
        const float* __restrict__ W2, unsigned short* __restrict__ Wtf2,
        const int* __restrict__ dst, uint32_t* __restrict__ ghist, int E){
    __shared__ uint32_t h[NBP];
    int bx = blockIdx.x, t = threadIdx.x;
    if (bx < NBLK_CONV){
        int i = bx * 256 + t;
        float4 a = ((const float4*)x)[2 * i];
        float4 b = ((const float4*)x)[2 * i + 1];
        u16x8 o = { f2bf(a.x), f2bf(a.y), f2bf(a.z), f2bf(a.w),
                    f2bf(b.x), f2bf(b.y), f2bf(b.z), f2bf(b.w) };
        ((u16x8*)Xh)[i] = o;
    } else if (bx < NBLK_CONV + NBLK_W){
        const int T1 = 8 * 4 * 64 * 8;   // 16384
        const int T2 = 3 * 4 * 64 * 8;   // 6144
        int i = (bx - NBLK_CONV) * 256 + t;
        if (i < T1){
            int j = i & 7, l = (i >> 3) & 63, st = (i >> 9) & 3, cb = i >> 11;
            int k = st * 32 + (l >> 4) * 8 + j, col = cb * 16 + (l & 15);
            Wtf1[i] = f2bf(W1[(size_t)k * 128 + col]);
        } else if (i < T1 + T2){
            int i2 = i - T1;
            int j = i2 & 7, l = (i2 >> 3) & 63, st = (i2 >> 9) & 3, cb = i2 >> 11;
            int k = st * 32 + (l >> 4) * 8 + j, col = cb * 16 + (l & 15);
            Wtf2[i2] = f2bf((col < 40) ? W2[(size_t)k * 40 + col] : 0.f);
        }
    } else {
        int bl = bx - NBLK_CONV - NBLK_W;
        for (int i = t; i < NBP; i += 256) h[i] = 0u;
        __syncthreads();
        int base = bl * EPB;
        for (int i = t; i < EPB; i += 256){
            int e = base + i;
            if (e < E) atomicAdd(&h[(uint32_t)dst[e] >> 7], 1u);
        }
        __syncthreads();
        for (int i = t; i < NBP; i += 256)
            ghist[bl * NBP + i] = h[i];
    }
}

// P2a: one block PER BUCKET: exclusive scan over the nblk per-block counts.
// part[blk][b] = prefix of blocks < blk for bucket b; hist[b] = total.
__global__ __launch_bounds__(256) void scan_blkcol(const uint32_t* __restrict__ ghist,
        uint32_t* __restrict__ part, uint32_t* __restrict__ hist, int nblk){
    __shared__ uint32_t tmp[256];
    int b = blockIdx.x, t = threadIdx.x;
    uint32_t v = (t < nblk) ? ghist[(size_t)t * NBP + b] : 0u;   // nblk = 200 <= 256
    tmp[t] = v;
    __syncthreads();
    for (int off = 1; off < 256; off <<= 1){
        uint32_t u = (t >= off) ? tmp[t - off] : 0u;
        __syncthreads();
        tmp[t] += u;
        __syncthreads();
    }
    if (t < nblk) part[(size_t)t * NBP + b] = tmp[t] - v;   // exclusive within column
    if (t == 0) hist[b] = tmp[255];                          // column total
}

// P2b: one block: exclusive scan of the NB bucket totals -> base.
__global__ __launch_bounds__(1024) void scan_base(const uint32_t* __restrict__ hist,
        uint32_t* __restrict__ base){
    __shared__ uint32_t tmp[1024];
    int t = threadIdx.x;
    uint32_t v = (t < NB) ? hist[t] : 0u;
    tmp[t] = v;
    __syncthreads();
    for (int off = 1; off < 1024; off <<= 1){
        uint32_t u = (t >= off) ? tmp[t - off] : 0u;
        __syncthreads();
        tmp[t] += u;
        __syncthreads();
    }
    if (t < NB) base[t] = tmp[t] - v;
}

// P3: scatter packed edges into bucket-sorted ebuf. No global atomics: block's
// start per bucket = base[b] + part[bl][b]; LDS atomics rank within block.
// packed = (dst & 127) << 17 | src   (src < 2^17)
__global__ __launch_bounds__(256) void bucket_scatter2(const int* __restrict__ src,
        const int* __restrict__ dst, const uint32_t* __restrict__ base,
        const uint32_t* __restrict__ part, uint32_t* __restrict__ ebuf, int E){
    __shared__ uint32_t rank[NBP];
    __shared__ uint32_t stl[NBP];
    int bl = blockIdx.x;
    for (int i = threadIdx.x; i < NBP; i += 256){
        rank[i] = 0u;
        stl[i] = base[i] + part[(size_t)bl * NBP + i];
    }
    __syncthreads();
    int eb0 = bl * EPB;
    for (int i = threadIdx.x; i < EPB; i += 256){
        int e = eb0 + i;
        if (e < E){
            uint32_t d = (uint32_t)dst[e];
            uint32_t b = d >> 7;
            uint32_t r = atomicAdd(&rank[b], 1u);
            ebuf[stl[b] + r] = ((d & 127u) << 17) | (uint32_t)src[e];
        }
    }
}

// P4: per bucket (128 nodes): LDS count -> LDS scan -> offs/cnt/dinv (dense),
// then rank edges per node -> slot within the bucket's contiguous region.
// slot holds plain src here; agg1 rewrites it to (q15(dinv[src])<<17)|src.
__global__ __launch_bounds__(256) void bucket_csr(const uint32_t* __restrict__ hist,
        const uint32_t* __restrict__ base, const uint32_t* __restrict__ ebuf,
        uint32_t* __restrict__ offs, uint32_t* __restrict__ cnt, float* __restrict__ dinv,
        uint32_t* __restrict__ slot, int N){
    __shared__ uint32_t ebl[BCAP];
    __shared__ uint32_t ncnt[128], loff[128], ncur[128], stmp[128];
    int b = blockIdx.x, t = threadIdx.x;
    uint32_t eb = base[b], ec = hist[b];
    if (ec > BCAP) ec = BCAP;            // unreachable safety
    for (uint32_t i = t; i < ec; i += 256) ebl[i] = ebuf[eb + i];
    if (t < 128){ ncnt[t] = 0u; ncur[t] = 0u; }
    __syncthreads();
    for (uint32_t i = t; i < ec; i += 256) atomicAdd(&ncnt[ebl[i] >> 17], 1u);
    __syncthreads();
    if (t < 128) stmp[t] = ncnt[t];
    __syncthreads();
    for (int off = 1; off < 128; off <<= 1){
        uint32_t v = 0u;
        if (t < 128 && t >= off) v = stmp[t - off];
        __syncthreads();
        if (t < 128) stmp[t] += v;
        __syncthreads();
    }
    if (t < 128) loff[t] = stmp[t] - ncnt[t];    // inclusive -> exclusive
    __syncthreads();
    int g = b * 128 + t;
    if (t < 128 && g < N){
        offs[g] = eb + loff[t];
        cnt[g]  = ncnt[t];
        dinv[g] = rsqrtf((float)(ncnt[t] + 1u));
    }
    for (uint32_t i = t; i < ec; i += 256){
        uint32_t p  = ebl[i];
        uint32_t ld = p >> 17;
        uint32_t r  = atomicAdd(&ncur[ld], 1u);
        slot[eb + loff[ld] + r] = p & 0x1FFFFu;
    }
}

// ---------------------------------------------------------------- aggregation kernel
// OUT[g] = dinv[g] * ( sum dinv[s]*X[s] + dinv[g]*X[g] ), bf16 rows.
// 4 nodes/wave (quarter-lanes), 16 lanes/node, u16x8 = 16B/lane.
// MODE 0 (layer 1): slot holds plain src; gather dinv[s] and REWRITE slot to
//   (q15(dinv[s])<<17) | s  (coalesced <=64B/node) so layer 2 skips the gather.
// MODE 1 (layer 2): decode weight from the slot word itself -- per-node chain
//   is slot -> row-gathers (3 RTs vs 4), no scattered dinv traffic.
template<int MODE>
__global__ __launch_bounds__(256) void agg_bf4(const unsigned short* __restrict__ Xh,
        const uint32_t* __restrict__ offs, const uint32_t* __restrict__ cnt,
        uint32_t* __restrict__ slot, const float* __restrict__ dinv,
        unsigned short* __restrict__ OUT){
    int wgid = blockIdx.x * 4 + (threadIdx.x >> 6);
    int l = threadIdx.x & 63;
    int ql = l & 15;
    int g = wgid * 4 + (l >> 4);                     // node id (grid exact)
    const u16x8* X8 = (const u16x8*)Xh;              // 16 u16x8 per 128-feat row
    uint32_t o = offs[g], c = cnt[g];
    float acc[8] = {};
    #pragma unroll 1
    for (uint32_t base = 0; base < c; base += 16){
        int rem = (int)(c - base); if (rem > 16) rem = 16;
        uint32_t idx = 0u; float ds = 0.f;
        if (ql < rem){
            uint32_t p = slot[o + base + (uint32_t)ql];
            if (MODE == 0){
                idx = p;
                ds = dinv[idx];
                uint32_t w = (uint32_t)(ds * 32767.f + 0.5f);
                if (w > 32767u) w = 32767u;
                slot[o + base + (uint32_t)ql] = (w << 17) | idx;   // pack for layer 2
            } else {
                idx = p & 0x1FFFFu;
                ds = (float)(p >> 17) * (1.f / 32767.f);
            }
        }
        int groups = (rem + 7) >> 3;
        #pragma unroll 1
        for (int gq = 0; gq < groups; gq++){
            int eb = gq * 8;
            u16x8 v[8]; float d[8];
            #pragma unroll
            for (int j = 0; j < 8; j++){
                int srcl = (l & 48) | (eb + j);
                uint32_t s = (uint32_t)__shfl((int)idx, srcl, 64);
                d[j] = __shfl(ds, srcl, 64);
                v[j] = X8[(size_t)s * 16 + ql];
            }
            #pragma unroll
            for (int j = 0; j < 8; j++){
                #pragma unroll
                for (int f = 0; f < 8; f++)
                    acc[f] += d[j] * bf2f(v[j][f]);
            }
        }
    }
    float dd = dinv[g];
    u16x8 sv = X8[(size_t)g * 16 + ql];
    u16x8 r;
    #pragma unroll
    for (int f = 0; f < 8; f++)
        r[f] = f2bf(dd * (acc[f] + dd * bf2f(sv[f])));
    ((u16x8*)OUT)[(size_t)g * 16 + ql] = r;
}

// ---------------------------------------------------------------- MFMA GEMM layer 1
// OUT = bf16( relu( Xagg @ W1 + b1 ) ). 4 waves/block, wave = 16 rows x 128 cols.
// Software pipeline with named register banks; B frags are single coalesced 1KB
// loads from fragment-order Wtf (L1/L2 resident).
__global__ __launch_bounds__(256) void gemm_mfma_l1(const unsigned short* __restrict__ Xagg,
        const unsigned short* __restrict__ Wtf, const float* __restrict__ bias,
        unsigned short* __restrict__ OUT){
    int tid = threadIdx.x;
    int wid = tid >> 6, l = tid & 63;
    int lm = l & 15, lk = l >> 4;
    int rw = blockIdx.x * 64 + wid * 16;
    int ra = rw + lm; ra = ra < N_NODES ? ra : N_NODES - 1;
    const bf16x8* Wv = (const bf16x8*)Wtf;

    f32x4 acc[8] = {};
    bf16x8 aA, aB, bA[8], bB[8];

    aA = *(const bf16x8*)(Xagg + (size_t)ra * 128 + lk * 8);
    #pragma unroll
    for (int cb = 0; cb < 8; cb++) bA[cb] = Wv[(size_t)(cb * 4 + 0) * 64 + l];

    aB = *(const bf16x8*)(Xagg + (size_t)ra * 128 + 32 + lk * 8);
    #pragma unroll
    for (int cb = 0; cb < 8; cb++) bB[cb] = Wv[(size_t)(cb * 4 + 1) * 64 + l];
    #pragma unroll
    for (int cb = 0; cb < 8; cb++)
        acc[cb] = __builtin_amdgcn_mfma_f32_16x16x32_bf16(aA, bA[cb], acc[cb], 0, 0, 0);

    aA = *(const bf16x8*)(Xagg + (size_t)ra * 128 + 64 + lk * 8);
    #pragma unroll
    for (int cb = 0; cb < 8; cb++) bA[cb] = Wv[(size_t)(cb * 4 + 2) * 64 + l];
    #pragma unroll
    for (int cb = 0; cb < 8; cb++)
        acc[cb] = __builtin_amdgcn_mfma_f32_16x16x32_bf16(aB, bB[cb], acc[cb], 0, 0, 0);

    aB = *(const bf16x8*)(Xagg + (size_t)ra * 128 + 96 + lk * 8);
    #pragma unroll
    for (int cb = 0; cb < 8; cb++) bB[cb] = Wv[(size_t)(cb * 4 + 3) * 64 + l];
    #pragma unroll
    for (int cb = 0; cb < 8; cb++)
        acc[cb] = __builtin_amdgcn_mfma_f32_16x16x32_bf16(aA, bA[cb], acc[cb], 0, 0, 0);

    #pragma unroll
    for (int cb = 0; cb < 8; cb++)
        acc[cb] = __builtin_amdgcn_mfma_f32_16x16x32_bf16(aB, bB[cb], acc[cb], 0, 0, 0);

    #pragma unroll
    for (int cb = 0; cb < 8; cb++){
        int col = cb * 16 + lm;
        float bs = bias[col];
        #pragma unroll
        for (int i = 0; i < 4; i++){
            int row = rw + lk * 4 + i;
            if (row < N_NODES)
                OUT[(size_t)row * 128 + col] = f2bf(fmaxf(acc[cb][i] + bs, 0.f));
        }
    }
}

// ---------------------------------------------------------------- MFMA GEMM layer 2
// OUT = Aagg @ W2 + b2 (fp32, 40 cols; Wtf2 padded to 48 cols with zeros).
__global__ __launch_bounds__(256) void gemm_mfma_l2(const unsigned short* __restrict__ Aagg,
        const unsigned short* __restrict__ Wtf, const float* __restrict__ bias,
        float* __restrict__ OUT){
    int tid = threadIdx.x;
    int wid = tid >> 6, l = tid & 63;
    int lm = l & 15, lk = l >> 4;
    int rw = blockIdx.x * 64 + wid * 16;
    int ra = rw + lm; ra = ra < N_NODES ? ra : N_NODES - 1;
    const bf16x8* Wv = (const bf16x8*)Wtf;

    f32x4 acc[3] = {};
    bf16x8 aA, aB, bA[3], bB[3];

    aA = *(const bf16x8*)(Aagg + (size_t)ra * 128 + lk * 8);
    #pragma unroll
    for (int cb = 0; cb < 3; cb++) bA[cb] = Wv[(size_t)(cb * 4 + 0) * 64 + l];

    aB = *(const bf16x8*)(Aagg + (size_t)ra * 128 + 32 + lk * 8);
    #pragma unroll
    for (int cb = 0; cb < 3; cb++) bB[cb] = Wv[(size_t)(cb * 4 + 1) * 64 + l];
    #pragma unroll
    for (int cb = 0; cb < 3; cb++)
        acc[cb] = __builtin_amdgcn_mfma_f32_16x16x32_bf16(aA, bA[cb], acc[cb], 0, 0, 0);

    aA = *(const bf16x8*)(Aagg + (size_t)ra * 128 + 64 + lk * 8);
    #pragma unroll
    for (int cb = 0; cb < 3; cb++) bA[cb] = Wv[(size_t)(cb * 4 + 2) * 64 + l];
    #pragma unroll
    for (int cb = 0; cb < 3; cb++)
        acc[cb] = __builtin_amdgcn_mfma_f32_16x16x32_bf16(aB, bB[cb], acc[cb], 0, 0, 0);

    aB = *(const bf16x8*)(Aagg + (size_t)ra * 128 + 96 + lk * 8);
    #pragma unroll
    for (int cb = 0; cb < 3; cb++) bB[cb] = Wv[(size_t)(cb * 4 + 3) * 64 + l];
    #pragma unroll
    for (int cb = 0; cb < 3; cb++)
        acc[cb] = __builtin_amdgcn_mfma_f32_16x16x32_bf16(aA, bA[cb], acc[cb], 0, 0, 0);

    #pragma unroll
    for (int cb = 0; cb < 3; cb++)
        acc[cb] = __builtin_amdgcn_mfma_f32_16x16x32_bf16(aB, bB[cb], acc[cb], 0, 0, 0);

    #pragma unroll
    for (int cb = 0; cb < 3; cb++){
        int col = cb * 16 + lm;
        if (col < 40){
            float bs = bias[col];
            #pragma unroll
            for (int i = 0; i < 4; i++){
                int row = rw + lk * 4 + i;
                if (row < N_NODES) OUT[(size_t)row * 40 + col] = acc[cb][i] + bs;
            }
        }
    }
}

// ---------------------------------------------------------------- launch
extern "C" void kernel_launch(void* const* d_in, const int* in_sizes, int n_in,
                              void* d_out, int out_size, void* d_ws, size_t ws_size,
                              hipStream_t stream) {
    const float* x   = (const float*)d_in[0];
    const int*   ei  = (const int*)d_in[1];      // int32 (harness converts integer inputs)
    const float* W1  = (const float*)d_in[2];
    const float* b1  = (const float*)d_in[3];
    const float* W2  = (const float*)d_in[4];
    const float* b2  = (const float*)d_in[5];
    float*       out = (float*)d_out;

    const int N = N_NODES;
    const int E = in_sizes[1] / 2;
    const int* src = ei;
    const int* dst = ei + E;

    // workspace carve-up (512B-aligned). ~83 MiB total (Xh aliased as Aagg2).
    char* ws = (char*)d_ws;
    size_t o = 0;
    auto alloc = [&](size_t bytes) -> char* {
        char* p = ws + o;
        o += (bytes + 511) & ~(size_t)511;
        return p;
    };
    const int nblk_edge = (E + EPB - 1) / EPB;    // 200
    uint32_t*       ghist = (uint32_t*)alloc((size_t)nblk_edge * NBP * 4);
    uint32_t*       part  = (uint32_t*)alloc((size_t)nblk_edge * NBP * 4);
    uint32_t*       hist  = (uint32_t*)alloc((size_t)NBP * 4);
    uint32_t*       bbase = (uint32_t*)alloc((size_t)NBP * 4);
    uint32_t*       ebuf  = (uint32_t*)alloc((size_t)E * 4);
    uint32_t*       offs  = (uint32_t*)alloc((size_t)N * 4);
    uint32_t*       cnt   = (uint32_t*)alloc((size_t)N * 4);
    uint32_t*       slot  = (uint32_t*)alloc((size_t)E * 4);
    float*          dinv  = (float*)alloc((size_t)N * 4);
    unsigned short* Wtf1  = (unsigned short*)alloc((size_t)8 * 4 * 64 * 8 * 2);  // 32 KB
    unsigned short* Wtf2  = (unsigned short*)alloc((size_t)3 * 4 * 64 * 8 * 2);  // 12 KB
    unsigned short* Xh    = (unsigned short*)alloc((size_t)N * 128 * 2);  // bf16 x; later Aagg2
    unsigned short* Xagg  = (unsigned short*)alloc((size_t)N * 128 * 2);  // aggregated x (bf16)
    unsigned short* Ah    = (unsigned short*)alloc((size_t)N * 128 * 2);  // layer-1 act (bf16)
    unsigned short* Aagg2 = Xh;   // Xh dead after agg1; reuse

    const int nblk_agg = N / 16;                  // 6250: 4 waves x 4 nodes/wave
    const int nblk_gemm = (N + 63) / 64;          // 1563

    // --- fused preamble (convert + W transpose + histogram) ---
    preamble<<<NBLK_CONV + NBLK_W + NBLK_HIST, 256, 0, stream>>>(
        x, Xh, W1, Wtf1, W2, Wtf2, dst, ghist, E);
    scan_blkcol<<<NB, 256, 0, stream>>>(ghist, part, hist, nblk_edge);
    scan_base<<<1, 1024, 0, stream>>>(hist, bbase);
    bucket_scatter2<<<nblk_edge, 256, 0, stream>>>(src, dst, bbase, part, ebuf, E);
    bucket_csr<<<NB, 256, 0, stream>>>(hist, bbase, ebuf, offs, cnt, dinv, slot, N);

    // --- layer 1 (agg1 packs edge weights into slot for agg2) ---
    agg_bf4<0><<<nblk_agg, 256, 0, stream>>>(Xh, offs, cnt, slot, dinv, Xagg);
    gemm_mfma_l1<<<nblk_gemm, 256, 0, stream>>>(Xagg, Wtf1, b1, Ah);

    // --- layer 2 (consumes packed weights) ---
    agg_bf4<1><<<nblk_agg, 256, 0, stream>>>(Ah, offs, cnt, slot, dinv, Aagg2);
    gemm_mfma_l2<<<nblk_gemm, 256, 0, stream>>>(Aagg2, Wtf2, b2, out);
}